// Round 7
// baseline (236.073 us; speedup 1.0000x reference)
//
#include <hip/hip_runtime.h>

#define B_DIM 32
#define C_DIM 64
#define D_DIM 64
#define T_DIM 30000
#define T4    7500
#define JTILE 128                 // floats of j per block (4 waves x 32)
#define TILES 235                 // ceil(30000 / 128)
#define NWG   (TILES * B_DIM)     // 7520, divisible by 8
#define ROWS  (B_DIM * C_DIM)     // 2048

typedef short bf16x8 __attribute__((ext_vector_type(8)));
typedef float f32x16 __attribute__((ext_vector_type(16)));
typedef float f32x4  __attribute__((ext_vector_type(4)));

__device__ __forceinline__ unsigned short f32_to_bf16_rne(float f) {
    unsigned int u = __builtin_bit_cast(unsigned int, f);
    return (unsigned short)((u + 0x7fffu + ((u >> 16) & 1u)) >> 16);
}

// ------- Kernel A: desc[b,c] = mean over T; last block computes attn2 -------
// attn2 = bf16(alpha * softmax((A*dc*de + Bq*dc + Bk*de + Cc)/8) + I)
__global__ __launch_bounds__(256) void mean_attn_kernel(const float* __restrict__ x,
                                                        const float* __restrict__ Wq,
                                                        const float* __restrict__ bq,
                                                        const float* __restrict__ Wk,
                                                        const float* __restrict__ bk,
                                                        const float* __restrict__ alphap,
                                                        float* __restrict__ desc,
                                                        unsigned short* __restrict__ attnb,
                                                        int* __restrict__ counter) {
    int r = blockIdx.x;  // b*64 + c
    const float4* xr = (const float4*)(x + (size_t)r * T_DIM);
    float4 s = {0.f, 0.f, 0.f, 0.f};
    for (int i = threadIdx.x; i < T4; i += 256) {
        float4 v = xr[i];
        s.x += v.x; s.y += v.y; s.z += v.z; s.w += v.w;
    }
    float p = (s.x + s.y) + (s.z + s.w);
    #pragma unroll
    for (int off = 32; off > 0; off >>= 1) p += __shfl_down(p, off, 64);
    __shared__ float wsum[4];
    int wave = threadIdx.x >> 6;
    int lane = threadIdx.x & 63;
    if (lane == 0) wsum[wave] = p;
    __syncthreads();

    __shared__ int win;
    if (threadIdx.x == 0) {
        float tot = (wsum[0] + wsum[1]) + (wsum[2] + wsum[3]);
        desc[r] = tot * (1.0f / (float)T_DIM);
        __threadfence();                         // release desc (device scope)
        win = (atomicAdd(counter, 1) == ROWS - 1);
    }
    __syncthreads();
    if (!win) return;
    __threadfence();                             // acquire all desc

    // ---- fused attn tail (one block, 256 threads; 3-pass, no big arrays) ----
    float dA = 0.f, dBq = 0.f, dBk = 0.f, dCc = 0.f;
    for (int d = 0; d < D_DIM; ++d) {
        float wq = Wq[d], wk = Wk[d], vq = bq[d], vk = bk[d];
        dA  += wq * wk;
        dBq += wq * vk;
        dBk += vq * wk;
        dCc += vq * vk;
    }
    float alpha = alphap[0];

    #pragma unroll
    for (int it = 0; it < 8; ++it) {
        int idx = threadIdx.x + 256 * it;        // (b,c) row of attn
        int b = idx >> 6, c = idx & 63;
        const float* db = desc + b * C_DIM;
        float dc = db[c];
        float base = dBq * dc + dCc;
        float coef = dA * dc + dBk;
        float lmax = -1e30f;
        for (int e = 0; e < C_DIM; ++e)
            lmax = fmaxf(lmax, (coef * db[e] + base) * 0.125f);
        float sum = 0.f;
        for (int e = 0; e < C_DIM; ++e)
            sum += __expf((coef * db[e] + base) * 0.125f - lmax);
        float inv = alpha / sum;
        unsigned short* arow = attnb + (size_t)idx * C_DIM;
        for (int e = 0; e < C_DIM; ++e) {
            float v = __expf((coef * db[e] + base) * 0.125f - lmax) * inv
                      + (e == c ? 1.0f : 0.0f);
            arow[e] = f32_to_bf16_rne(v);
        }
    }
}

// ---------------- Kernel C: out = attn2 @ x via bf16 MFMA, LDS-staged ----------------
// R5 structure (proven 118us total) + anti-LRU reversed tile order: mean left
// the high-t tail of x L3-hottest, so consume high-t tiles first.
__global__ __launch_bounds__(256) void mix_mfma(const float* __restrict__ x,
                                                const unsigned short* __restrict__ attnb,
                                                float* __restrict__ out) {
    __shared__ float lx[C_DIM][JTILE];   // 32 KB; x-tile, then out-tile

    // chunked XCD swizzle: same-b adjacent tiles stay on one XCD's L2
    int flat = blockIdx.x;
    int swz  = (flat & 7) * (NWG / 8) + (flat >> 3);
    int b    = swz / TILES;
    int tile = (TILES - 1) - (swz % TILES);   // reversed: high-t first

    int t   = threadIdx.x;
    int w   = t >> 6;
    int l31 = t & 31;
    int lhi = (t >> 5) & 1;

    // ---- A fragments (attn2, bf16) — issue first, fly under the staging barrier
    const unsigned short* ab = attnb + (size_t)b * C_DIM * C_DIM;
    bf16x8 afrag[2][4];
    #pragma unroll
    for (int m = 0; m < 2; ++m)
        #pragma unroll
        for (int g = 0; g < 4; ++g)
            afrag[m][g] = *(const bf16x8*)(ab + (32 * m + l31) * C_DIM + 16 * g + 8 * lhi);

    // ---- stage x tile: 8 coalesced float4 loads -> ds_write_b128
    const float* xb = x + (size_t)b * C_DIM * T_DIM;
    int cf4  = t & 31;                 // float4 col within tile
    int jf4  = tile * 32 + cf4;        // global float4 col
    int jf4c = (jf4 < T4) ? jf4 : (T4 - 1);
    #pragma unroll
    for (int p = 0; p < 8; ++p) {
        int e = p * 8 + (t >> 5);
        f32x4 v = *(const f32x4*)(xb + (size_t)e * T_DIM + (size_t)jf4c * 4);
        *(f32x4*)&lx[e][cf4 * 4] = v;
    }
    __syncthreads();

    // ---- compute: B-frags from LDS (conflict-free ds_read_b32), cvt, MFMA
    int jc = w * 32 + l31;             // this lane's j col within tile
    f32x16 acc0 = {}, acc1 = {};
    #pragma unroll
    for (int g = 0; g < 4; ++g) {
        int e0 = 16 * g + 8 * lhi;
        bf16x8 bfrag;
        #pragma unroll
        for (int i = 0; i < 8; ++i)
            bfrag[i] = (short)f32_to_bf16_rne(lx[e0 + i][jc]);
        acc0 = __builtin_amdgcn_mfma_f32_32x32x16_bf16(afrag[0][g], bfrag, acc0, 0, 0, 0);
        acc1 = __builtin_amdgcn_mfma_f32_32x32x16_bf16(afrag[1][g], bfrag, acc1, 0, 0, 0);
    }
    __syncthreads();

    // ---- write acc to LDS out-tile (bank = l31, conflict-free)
    #pragma unroll
    for (int r = 0; r < 16; ++r) {
        int crow = (r & 3) + 8 * (r >> 2) + 4 * lhi;
        lx[crow][jc]      = acc0[r];
        lx[crow + 32][jc] = acc1[r];
    }
    __syncthreads();

    // ---- cooperative store-out: ds_read_b128 -> nontemporal dwordx4
    if (jf4 < T4) {
        float* ob = out + (size_t)b * C_DIM * T_DIM;
        #pragma unroll
        for (int p = 0; p < 8; ++p) {
            int e = p * 8 + (t >> 5);
            f32x4 v = *(const f32x4*)&lx[e][cf4 * 4];
            __builtin_nontemporal_store(v, (f32x4*)(ob + (size_t)e * T_DIM + (size_t)jf4 * 4));
        }
    }
}

extern "C" void kernel_launch(void* const* d_in, const int* in_sizes, int n_in,
                              void* d_out, int out_size, void* d_ws, size_t ws_size,
                              hipStream_t stream) {
    const float* x     = (const float*)d_in[0];
    const float* Wq    = (const float*)d_in[1];
    const float* bq    = (const float*)d_in[2];
    const float* Wk    = (const float*)d_in[3];
    const float* bk    = (const float*)d_in[4];
    // d_in[5] = Wv, d_in[6] = bv: dead code in the reference
    const float* alpha = (const float*)d_in[7];
    float* out = (float*)d_out;

    float* desc = (float*)d_ws;                                       // 8 KB
    unsigned short* attnb = (unsigned short*)(desc + ROWS);           // 256 KB bf16
    int* counter = (int*)(attnb + (size_t)B_DIM * C_DIM * C_DIM);

    hipMemsetAsync(counter, 0, sizeof(int), stream);   // deterministic; capture-legal
    mean_attn_kernel<<<ROWS, 256, 0, stream>>>(x, Wq, bq, Wk, bk, alpha,
                                               desc, attnb, counter);
    mix_mfma<<<NWG, 256, 0, stream>>>(x, attnb, out);
}

// Round 8
// 138.394 us; speedup vs baseline: 1.7058x; 1.7058x over previous
//
#include <hip/hip_runtime.h>

#define B_DIM 32
#define C_DIM 64
#define D_DIM 64
#define T_DIM 30000
#define T4    7500
#define T8    3750
#define JTILE 128                 // j columns per mix tile
#define TILES 235                 // ceil(30000 / 128)
#define NWG   (TILES * B_DIM)     // 7520, divisible by 8
#define ROWS  (B_DIM * C_DIM)     // 2048

typedef short bf16x8 __attribute__((ext_vector_type(8)));
typedef float f32x16 __attribute__((ext_vector_type(16)));
typedef float f32x4  __attribute__((ext_vector_type(4)));
typedef unsigned short u16x8 __attribute__((ext_vector_type(8)));

__device__ __forceinline__ unsigned short f32_to_bf16_rne(float f) {
    unsigned int u = __builtin_bit_cast(unsigned int, f);
    return (unsigned short)((u + 0x7fffu + ((u >> 16) & 1u)) >> 16);
}

// ======================= PATH 1 (big workspace) =======================

// ---- Kernel A1: desc = mean(x); also emit bf16(x) to workspace.
// x read NON-TEMPORALLY (read-once, don't allocate L3); bf16x written
// normally so the 123 MB bf16 copy is what lives in L3 for mix.
__global__ __launch_bounds__(256) void mean_bf16_kernel(const float* __restrict__ x,
                                                        float* __restrict__ desc,
                                                        unsigned short* __restrict__ xb) {
    int r = blockIdx.x;  // b*64 + c
    const f32x4* xr = (const f32x4*)(x + (size_t)r * T_DIM);
    u16x8* br = (u16x8*)(xb + (size_t)r * T_DIM);
    f32x4 s = {0.f, 0.f, 0.f, 0.f};
    for (int i = threadIdx.x; i < T8; i += 256) {
        f32x4 a = __builtin_nontemporal_load(xr + 2 * i);
        f32x4 c = __builtin_nontemporal_load(xr + 2 * i + 1);
        s += a; s += c;
        u16x8 v;
        #pragma unroll
        for (int q = 0; q < 4; ++q) v[q]     = f32_to_bf16_rne(a[q]);
        #pragma unroll
        for (int q = 0; q < 4; ++q) v[4 + q] = f32_to_bf16_rne(c[q]);
        br[i] = v;
    }
    float p = (s.x + s.y) + (s.z + s.w);
    #pragma unroll
    for (int off = 32; off > 0; off >>= 1) p += __shfl_down(p, off, 64);
    __shared__ float wsum[4];
    int wave = threadIdx.x >> 6;
    int lane = threadIdx.x & 63;
    if (lane == 0) wsum[wave] = p;
    __syncthreads();
    if (threadIdx.x == 0) {
        float tot = (wsum[0] + wsum[1]) + (wsum[2] + wsum[3]);
        desc[r] = tot * (1.0f / (float)T_DIM);
    }
}

// ---- Kernel C1: out = attn2 @ bf16x via MFMA; 16 KB LDS tile, out-bounce reuse.
__global__ __launch_bounds__(256) void mix_bf16(const unsigned short* __restrict__ xb,
                                                const unsigned short* __restrict__ attnb,
                                                float* __restrict__ out) {
    __shared__ unsigned short lh[C_DIM][JTILE];   // 16 KB; bf16 x-tile, then f32 out-tile

    int flat = blockIdx.x;
    int swz  = (flat & 7) * (NWG / 8) + (flat >> 3);
    int b    = swz / TILES;
    int tile = swz % TILES;

    int t   = threadIdx.x;
    int w   = t >> 6;
    int l31 = t & 31;
    int lhi = (t >> 5) & 1;

    // A fragments first (L2-resident; fly under staging)
    const unsigned short* ab = attnb + (size_t)b * C_DIM * C_DIM;
    bf16x8 afrag[2][4];
    #pragma unroll
    for (int m = 0; m < 2; ++m)
        #pragma unroll
        for (int g = 0; g < 4; ++g)
            afrag[m][g] = *(const bf16x8*)(ab + (32 * m + l31) * C_DIM + 16 * g + 8 * lhi);

    // stage bf16 x-tile: 1024 chunks of 16B (row e, 8-col group c8)
    const unsigned short* xrow = xb + (size_t)b * C_DIM * T_DIM;
    #pragma unroll
    for (int p = 0; p < 4; ++p) {
        int chunk = t + 256 * p;
        int e  = chunk >> 4;
        int c8 = chunk & 15;
        int j0 = tile * JTILE + c8 * 8;
        if (j0 > T_DIM - 8) j0 = T_DIM - 8;   // row-local clamp (last tile)
        u16x8 v = *(const u16x8*)(xrow + (size_t)e * T_DIM + j0);
        *(u16x8*)&lh[e][c8 * 8] = v;
    }
    __syncthreads();

    // compute: bfrag straight from LDS (already bf16), 8 MFMA
    int jc = w * 32 + l31;
    f32x16 acc0 = {}, acc1 = {};
    #pragma unroll
    for (int g = 0; g < 4; ++g) {
        int e0 = 16 * g + 8 * lhi;
        bf16x8 bfrag;
        #pragma unroll
        for (int i = 0; i < 8; ++i)
            bfrag[i] = (short)lh[e0 + i][jc];
        acc0 = __builtin_amdgcn_mfma_f32_32x32x16_bf16(afrag[0][g], bfrag, acc0, 0, 0, 0);
        acc1 = __builtin_amdgcn_mfma_f32_32x32x16_bf16(afrag[1][g], bfrag, acc1, 0, 0, 0);
    }
    __syncthreads();   // all LDS reads done before out-bounce overwrites

    // epilogue: bounce each 32-row half through LDS (f32 [32][128] = 16 KB)
    float (*o)[JTILE] = (float (*)[JTILE]) &lh[0][0];
    float* ob = out + (size_t)b * C_DIM * T_DIM;
    #pragma unroll
    for (int h = 0; h < 2; ++h) {
        #pragma unroll
        for (int r = 0; r < 16; ++r) {
            int crow = (r & 3) + 8 * (r >> 2) + 4 * lhi;
            o[crow][jc] = h ? acc1[r] : acc0[r];
        }
        __syncthreads();
        #pragma unroll
        for (int p = 0; p < 4; ++p) {
            int chunk = t + 256 * p;       // 1024 f32x4 chunks: row = chunk>>5, c4 = chunk&31
            int row = chunk >> 5;
            int c4  = chunk & 31;
            int gcol = tile * JTILE + c4 * 4;
            if (gcol + 3 < T_DIM) {
                f32x4 v = *(const f32x4*)&o[row][c4 * 4];
                __builtin_nontemporal_store(
                    v, (f32x4*)(ob + (size_t)(h * 32 + row) * T_DIM + gcol));
            }
        }
        __syncthreads();
    }
}

// ======================= PATH 2 (fallback = R5 exact) =======================

__global__ __launch_bounds__(256) void mean_kernel(const float* __restrict__ x,
                                                   float* __restrict__ desc) {
    int r = blockIdx.x;
    const float4* xr = (const float4*)(x + (size_t)r * T_DIM);
    float4 s = {0.f, 0.f, 0.f, 0.f};
    for (int i = threadIdx.x; i < T4; i += 256) {
        float4 v = xr[i];
        s.x += v.x; s.y += v.y; s.z += v.z; s.w += v.w;
    }
    float p = (s.x + s.y) + (s.z + s.w);
    #pragma unroll
    for (int off = 32; off > 0; off >>= 1) p += __shfl_down(p, off, 64);
    __shared__ float wsum[4];
    int wave = threadIdx.x >> 6;
    int lane = threadIdx.x & 63;
    if (lane == 0) wsum[wave] = p;
    __syncthreads();
    if (threadIdx.x == 0) {
        float tot = (wsum[0] + wsum[1]) + (wsum[2] + wsum[3]);
        desc[r] = tot * (1.0f / (float)T_DIM);
    }
}

__global__ __launch_bounds__(256) void mix_mfma(const float* __restrict__ x,
                                                const unsigned short* __restrict__ attnb,
                                                float* __restrict__ out) {
    __shared__ float lx[C_DIM][JTILE];   // 32 KB

    int flat = blockIdx.x;
    int swz  = (flat & 7) * (NWG / 8) + (flat >> 3);
    int b    = swz / TILES;
    int tile = swz % TILES;

    int t   = threadIdx.x;
    int w   = t >> 6;
    int l31 = t & 31;
    int lhi = (t >> 5) & 1;

    const unsigned short* ab = attnb + (size_t)b * C_DIM * C_DIM;
    bf16x8 afrag[2][4];
    #pragma unroll
    for (int m = 0; m < 2; ++m)
        #pragma unroll
        for (int g = 0; g < 4; ++g)
            afrag[m][g] = *(const bf16x8*)(ab + (32 * m + l31) * C_DIM + 16 * g + 8 * lhi);

    const float* xbp = x + (size_t)b * C_DIM * T_DIM;
    int cf4  = t & 31;
    int jf4  = tile * 32 + cf4;
    int jf4c = (jf4 < T4) ? jf4 : (T4 - 1);
    #pragma unroll
    for (int p = 0; p < 8; ++p) {
        int e = p * 8 + (t >> 5);
        f32x4 v = *(const f32x4*)(xbp + (size_t)e * T_DIM + (size_t)jf4c * 4);
        *(f32x4*)&lx[e][cf4 * 4] = v;
    }
    __syncthreads();

    int jc = w * 32 + l31;
    f32x16 acc0 = {}, acc1 = {};
    #pragma unroll
    for (int g = 0; g < 4; ++g) {
        int e0 = 16 * g + 8 * lhi;
        bf16x8 bfrag;
        #pragma unroll
        for (int i = 0; i < 8; ++i)
            bfrag[i] = (short)f32_to_bf16_rne(lx[e0 + i][jc]);
        acc0 = __builtin_amdgcn_mfma_f32_32x32x16_bf16(afrag[0][g], bfrag, acc0, 0, 0, 0);
        acc1 = __builtin_amdgcn_mfma_f32_32x32x16_bf16(afrag[1][g], bfrag, acc1, 0, 0, 0);
    }
    __syncthreads();

    #pragma unroll
    for (int r = 0; r < 16; ++r) {
        int crow = (r & 3) + 8 * (r >> 2) + 4 * lhi;
        lx[crow][jc]      = acc0[r];
        lx[crow + 32][jc] = acc1[r];
    }
    __syncthreads();

    if (jf4 < T4) {
        float* ob = out + (size_t)b * C_DIM * T_DIM;
        #pragma unroll
        for (int p = 0; p < 8; ++p) {
            int e = p * 8 + (t >> 5);
            f32x4 v = *(const f32x4*)&lx[e][cf4 * 4];
            __builtin_nontemporal_store(v, (f32x4*)(ob + (size_t)e * T_DIM + (size_t)jf4 * 4));
        }
    }
}

// ======================= shared attn kernel =======================

__global__ __launch_bounds__(64) void attn_kernel(const float* __restrict__ desc,
                                                  const float* __restrict__ Wq,
                                                  const float* __restrict__ bq,
                                                  const float* __restrict__ Wk,
                                                  const float* __restrict__ bk,
                                                  const float* __restrict__ alphap,
                                                  unsigned short* __restrict__ attnb) {
    int b = blockIdx.x;
    int c = threadIdx.x;
    __shared__ float sd[C_DIM];
    sd[c] = desc[b * C_DIM + c];
    __syncthreads();

    float dA = 0.f, dBq = 0.f, dBk = 0.f, dCc = 0.f;
    #pragma unroll
    for (int d = 0; d < D_DIM; ++d) {
        float wq = Wq[d], wk = Wk[d], vq = bq[d], vk = bk[d];
        dA  += wq * wk;
        dBq += wq * vk;
        dBk += vq * wk;
        dCc += vq * vk;
    }

    float dc = sd[c];
    float l[C_DIM];
    float lmax = -1e30f;
    #pragma unroll
    for (int e = 0; e < C_DIM; ++e) {
        float de = sd[e];
        float v = (dA * dc * de + dBq * dc + dBk * de + dCc) * 0.125f;
        l[e] = v;
        lmax = fmaxf(lmax, v);
    }
    float sum = 0.f;
    #pragma unroll
    for (int e = 0; e < C_DIM; ++e) {
        float ev = __expf(l[e] - lmax);
        l[e] = ev;
        sum += ev;
    }
    float inv = alphap[0] / sum;
    unsigned short* arow = attnb + ((size_t)b * C_DIM + c) * C_DIM;
    #pragma unroll
    for (int e = 0; e < C_DIM; ++e) {
        float v = l[e] * inv + (e == c ? 1.0f : 0.0f);
        arow[e] = f32_to_bf16_rne(v);
    }
}

extern "C" void kernel_launch(void* const* d_in, const int* in_sizes, int n_in,
                              void* d_out, int out_size, void* d_ws, size_t ws_size,
                              hipStream_t stream) {
    const float* x     = (const float*)d_in[0];
    const float* Wq    = (const float*)d_in[1];
    const float* bq    = (const float*)d_in[2];
    const float* Wk    = (const float*)d_in[3];
    const float* bk    = (const float*)d_in[4];
    const float* alpha = (const float*)d_in[7];
    float* out = (float*)d_out;

    float* desc = (float*)d_ws;                                   // 8 KB
    unsigned short* attnb = (unsigned short*)(desc + ROWS);       // 256 KB
    unsigned short* xb = attnb + (size_t)B_DIM * C_DIM * C_DIM;   // 122.88 MB (path 1)

    size_t need = (size_t)ROWS * 4 + (size_t)B_DIM * C_DIM * C_DIM * 2
                + (size_t)B_DIM * C_DIM * T_DIM * 2;

    if (ws_size >= need) {
        mean_bf16_kernel<<<ROWS, 256, 0, stream>>>(x, desc, xb);
        attn_kernel<<<B_DIM, 64, 0, stream>>>(desc, Wq, bq, Wk, bk, alpha, attnb);
        mix_bf16<<<NWG, 256, 0, stream>>>(xb, attnb, out);
    } else {
        mean_kernel<<<ROWS, 256, 0, stream>>>(x, desc);
        attn_kernel<<<B_DIM, 64, 0, stream>>>(desc, Wq, bq, Wk, bk, alpha, attnb);
        mix_mfma<<<NWG, 256, 0, stream>>>(x, attnb, out);
    }
}